// Round 16
// baseline (26648.682 us; speedup 1.0000x reference)
//
#include <hip/hip_runtime.h>
#include <hip/hip_bf16.h>
#include <math.h>

#define B 64
#define T 128
#define S 128
#define E 512
#define H 1024
#define D 1024
#define KDIM 1024
#define G3 3072

__device__ __forceinline__ float sigmoidf_(float x) { return 1.f / (1.f + expf(-x)); }

// ---------------------------------------------------------------------------
// 128x128-tile f32 GEMM (proven R5/R8/R10/R15). SRC 0: plain A. SRC 1: rows
// (b,tl) -> reversed_input (K=512). SRC 2: rows (b,tl) -> [y_states|rnn_flip].
// ---------------------------------------------------------------------------
template<int SRC>
__global__ __launch_bounds__(256) void gemm128(
    const float* __restrict__ A1, const float* __restrict__ A2, int lda,
    const float* __restrict__ W, int ldw, const float* __restrict__ bias,
    float* __restrict__ C, int ldc, int Kd, int c0, int chLog) {
  __shared__ __align__(16) float As[16][132];
  __shared__ __align__(16) float Ws[16][132];
  const int bm = blockIdx.y * 128;
  const int bn = blockIdx.x * 128;
  const int tid = threadIdx.x;
  const int tr = tid >> 4, tc = tid & 15;
  float acc[8][8];
#pragma unroll
  for (int i = 0; i < 8; ++i)
#pragma unroll
    for (int j = 0; j < 8; ++j) acc[i][j] = 0.f;

  for (int k0 = 0; k0 < Kd; k0 += 16) {
#pragma unroll
    for (int l = 0; l < 8; ++l) {
      int i = tid + l * 256;
      int r = i >> 4, kk = i & 15;
      int rg = bm + r;
      int k = k0 + kk;
      float v;
      if (SRC == 0) {
        v = A1[(size_t)rg * lda + k];
      } else {
        int b = rg >> chLog, tl = rg & ((1 << chLog) - 1);
        int trow = b * T + c0 + tl;
        if (SRC == 1) v = A1[(size_t)trow * E + k];
        else v = (k < 1024) ? A1[(size_t)trow * 1024 + k]
                            : A2[(size_t)trow * 1024 + (k - 1024)];
      }
      As[kk][r] = v;
    }
#pragma unroll
    for (int l = 0; l < 8; ++l) {
      int i = tid + l * 256;
      int c = i >> 4, kk = i & 15;
      Ws[kk][c] = W[(size_t)(bn + c) * ldw + k0 + kk];
    }
    __syncthreads();
#pragma unroll
    for (int kk = 0; kk < 16; ++kk) {
      float a[8], w[8];
      *(float4*)&a[0] = *(const float4*)&As[kk][tr * 8];
      *(float4*)&a[4] = *(const float4*)&As[kk][tr * 8 + 4];
      *(float4*)&w[0] = *(const float4*)&Ws[kk][tc * 8];
      *(float4*)&w[4] = *(const float4*)&Ws[kk][tc * 8 + 4];
#pragma unroll
      for (int i = 0; i < 8; ++i)
#pragma unroll
        for (int j = 0; j < 8; ++j)
          acc[i][j] = fmaf(a[i], w[j], acc[i][j]);
    }
    __syncthreads();
  }
#pragma unroll
  for (int i = 0; i < 8; ++i) {
    int rg = bm + tr * 8 + i;
#pragma unroll
    for (int j = 0; j < 8; ++j) {
      int cc = bn + tc * 8 + j;
      float bv = bias ? bias[cc] : 0.f;
      C[(size_t)rg * ldc + cc] = acc[i][j] + bv;
    }
  }
}

// ---------------------------------------------------------------------------
// Scalar-broadcast skinny GEMM, templated rows/block (R15 two-pass A cache).
// JTT=16: scan-1 (384 blocks). JTT=32: scan-2 gates (576 blocks, halved
// A-gather traffic). Partials [seg][b][j].
// ---------------------------------------------------------------------------
struct SBSeg { const float* A; const float* W; int lda; int ldw; int N; };
struct SBArgs { SBSeg s[6]; };

template<int JTT>
__global__ __launch_bounds__(256) void sb_gemm(SBArgs args, int jtPerSeg, int Nstr,
                                               float* __restrict__ part) {
  const int seg = blockIdx.x / jtPerSeg;
  const int jt = blockIdx.x % jtPerSeg;
  const SBSeg sg = args.s[seg];
  const int j0 = jt * JTT;
  if (j0 >= sg.N) return;
  const int wv = __builtin_amdgcn_readfirstlane(threadIdx.x >> 6);
  const int lane = threadIdx.x & 63;
  float acc[JTT];
#pragma unroll
  for (int jj = 0; jj < JTT; ++jj) acc[jj] = 0.f;
#pragma unroll 1
  for (int half = 0; half < 2; ++half) {
    const int kw = wv * 128 + half * 64;
    float a[64];
    const float4* ap = (const float4*)(sg.A + (size_t)lane * sg.lda + kw);
#pragma unroll
    for (int q = 0; q < 16; ++q) {
      float4 v = ap[q];
      a[q * 4 + 0] = v.x; a[q * 4 + 1] = v.y; a[q * 4 + 2] = v.z; a[q * 4 + 3] = v.w;
    }
#pragma unroll
    for (int jj = 0; jj < JTT; ++jj) {
      int j = j0 + jj;
      if (j < sg.N) {
        const float4* wp = (const float4*)(sg.W + (size_t)j * sg.ldw + kw);
        float s0 = 0.f, s1 = 0.f, s2 = 0.f, s3 = 0.f;
#pragma unroll
        for (int q = 0; q < 16; ++q) {
          float4 w4 = wp[q];
          s0 = fmaf(a[q * 4 + 0], w4.x, s0);
          s1 = fmaf(a[q * 4 + 1], w4.y, s1);
          s2 = fmaf(a[q * 4 + 2], w4.z, s2);
          s3 = fmaf(a[q * 4 + 3], w4.w, s3);
        }
        acc[jj] += (s0 + s1) + (s2 + s3);
      }
    }
  }
  __shared__ float red[4][JTT][64];
#pragma unroll
  for (int jj = 0; jj < JTT; ++jj) red[wv][jj][lane] = acc[jj];
  __syncthreads();
  for (int idx = threadIdx.x; idx < JTT * 64; idx += 256) {
    int b = idx / JTT, jj = idx % JTT;
    int j = j0 + jj;
    if (j < sg.N) {
      float v = red[0][jj][b] + red[1][jj][b] + red[2][jj][b] + red[3][jj][b];
      part[((size_t)seg * 64 + b) * Nstr + j] = v;
    }
  }
}

// ---------------------------------------------------------------------------
// GRU cell, fully coalesced (R10-proven verbatim). Grid 256 x 256 thr.
// ---------------------------------------------------------------------------
__global__ __launch_bounds__(256) void gru_reduce(
    const float* __restrict__ part, const float* __restrict__ gi,
    int CH, int tl, int nsGi, int ghStart, int nsGh,
    const float* __restrict__ bhh, float* __restrict__ hrow,
    float* __restrict__ flip_out, int t) {
  const int b = blockIdx.x >> 2;
  const int j = (blockIdx.x & 3) * 256 + threadIdx.x;
  const float* gb = gi + (size_t)(b * CH + tl) * G3;
  float gir = gb[j];
  float giz = gb[H + j];
  float gin = gb[2 * H + j];
  for (int p2 = 0; p2 < nsGi; ++p2) {
    const float* pp = part + ((size_t)p2 * 64 + b) * G3;
    gir += pp[j]; giz += pp[H + j]; gin += pp[2 * H + j];
  }
  float ghr = bhh[j], ghz = bhh[H + j], ghn = bhh[2 * H + j];
  for (int p2 = ghStart; p2 < ghStart + nsGh; ++p2) {
    const float* pp = part + ((size_t)p2 * 64 + b) * G3;
    ghr += pp[j]; ghz += pp[H + j]; ghn += pp[2 * H + j];
  }
  float r = sigmoidf_(gir + ghr);
  float z = sigmoidf_(giz + ghz);
  float n = tanhf(gin + r * ghn);
  float hold = hrow[(size_t)b * H + j];
  float hnew = (1.f - z) * n + z * hold;
  hrow[(size_t)b * H + j] = hnew;
  if (flip_out)
    flip_out[(size_t)b * T * H + (size_t)(T - 1 - t) * H + j] = hnew;
}

// ---------------------------------------------------------------------------
// h-projections, full K=1024 in-block. Grid 385 (R10-proven verbatim).
// ---------------------------------------------------------------------------
__global__ __launch_bounds__(256) void hproj_gemm(
    const float* __restrict__ h,
    const float* __restrict__ corrW, const float* __restrict__ corrB,
    const float* __restrict__ qW, const float* __restrict__ avW,
    const float* __restrict__ rewW, const float* __restrict__ rewB,
    float* __restrict__ corrR, float* __restrict__ pq,
    float* __restrict__ attH, float* __restrict__ rew,
    float* __restrict__ out_rewards, int t) {
  const int task = blockIdx.x;
  const int tid = threadIdx.x;
  const int wv = __builtin_amdgcn_readfirstlane(tid >> 6);
  const int lane = tid & 63;
  const float* Wb; int ldw = 1024, n0, nrows, typ;
  if (task < 128)      { Wb = corrW; n0 = task * 8;         nrows = 8; typ = 0; }
  else if (task < 256) { Wb = qW;    n0 = (task - 128) * 8; nrows = 8; typ = 1; }
  else if (task < 384) { Wb = avW;   n0 = (task - 256) * 8; nrows = 8; typ = 2; ldw = 2048; }
  else                 { Wb = rewW;  n0 = 0;                nrows = 2; typ = 3; }
  const int k0 = wv * 256;
  const float* arow = h + (size_t)lane * H + k0;
  float acc[8] = {0.f, 0.f, 0.f, 0.f, 0.f, 0.f, 0.f, 0.f};
  for (int sc = 0; sc < 8; ++sc) {
    float av[32];
    const float4* ap = (const float4*)(arow + sc * 32);
#pragma unroll
    for (int q = 0; q < 8; ++q) {
      float4 v = ap[q];
      av[4*q] = v.x; av[4*q+1] = v.y; av[4*q+2] = v.z; av[4*q+3] = v.w;
    }
#pragma unroll
    for (int rr = 0; rr < 8; ++rr) {
      if (rr < nrows) {
        const float4* wp = (const float4*)(Wb + (size_t)(n0 + rr) * ldw + k0 + sc * 32);
        float s = acc[rr];
#pragma unroll
        for (int q = 0; q < 8; ++q) {
          float4 w = wp[q];
          s = fmaf(av[4*q],   w.x, s);
          s = fmaf(av[4*q+1], w.y, s);
          s = fmaf(av[4*q+2], w.z, s);
          s = fmaf(av[4*q+3], w.w, s);
        }
        acc[rr] = s;
      }
    }
  }
  __shared__ float red[4][8][64];
#pragma unroll
  for (int rr = 0; rr < 8; ++rr) red[wv][rr][lane] = acc[rr];
  __syncthreads();
  for (int idx = tid; idx < 512; idx += 256) {
    int b = idx >> 3, jj = idx & 7;
    if (jj < nrows) {
      int n = n0 + jj;
      float v = red[0][jj][b] + red[1][jj][b] + red[2][jj][b] + red[3][jj][b];
      if (typ == 0) corrR[(size_t)b * 1024 + n] = v + corrB[n];
      else if (typ == 1) pq[(size_t)b * 1024 + n] = v;
      else if (typ == 2) attH[(size_t)n * 64 + b] = v;
      else {
        float rv = v + rewB[n];
        rew[n * 64 + b] = rv;
        out_rewards[((size_t)b * T + t) * 2 + n] = rv;
      }
    }
  }
}

// energies: wave per (b,s). Grid 2048 x 256. (R3/R10-proven verbatim.)
__global__ __launch_bounds__(256) void energy_kernel(
    const float* __restrict__ pq, const float* __restrict__ pk,
    const float* __restrict__ eW, float* __restrict__ energies) {
  int wid = blockIdx.x * 4 + (threadIdx.x >> 6);
  int lane = threadIdx.x & 63;
  int b = wid >> 7, s = wid & 127;
  const float* pkp = pk + ((size_t)b * S + s) * H;
  const float* qp = pq + (size_t)b * H;
  float acc = 0.f;
#pragma unroll
  for (int i = 0; i < 16; ++i) {
    int j = lane + i * 64;
    acc += tanhf(qp[j] + pkp[j]) * eW[j];
  }
#pragma unroll
  for (int off = 32; off > 0; off >>= 1) acc += __shfl_down(acc, off);
  if (lane == 0) energies[b * S + s] = acc;
}

// Softmax (redundant per kt) + context + corr finalize + outputs.
// Grid (64, 4) x 256. (R10-proven verbatim.)
__global__ __launch_bounds__(256) void smct_plus(
    const float* __restrict__ energies, const float* __restrict__ enc,
    const float* __restrict__ corrR, const float* __restrict__ rew,
    float* __restrict__ ctx, float* __restrict__ uv,
    float* __restrict__ out_attns, float* __restrict__ out_corrs, int t) {
  int b = blockIdx.x, kt = blockIdx.y;
  int tid = threadIdx.x;
  __shared__ float se[128], sa[128], ss[128];
  if (tid < 128) { se[tid] = energies[b * S + tid]; sa[tid] = se[tid]; }
  __syncthreads();
  for (int st2 = 64; st2 > 0; st2 >>= 1) {
    if (tid < st2) sa[tid] = fmaxf(sa[tid], sa[tid + st2]);
    __syncthreads();
  }
  float mx = sa[0];
  __syncthreads();
  if (tid < 128) { sa[tid] = expf(se[tid] - mx); ss[tid] = sa[tid]; }
  __syncthreads();
  for (int st2 = 64; st2 > 0; st2 >>= 1) {
    if (tid < st2) ss[tid] += ss[tid + st2];
    __syncthreads();
  }
  float inv = 1.f / ss[0];
  __syncthreads();
  if (tid < 128) sa[tid] *= inv;
  __syncthreads();
  int k = kt * 256 + tid;
  const float* eb = enc + (size_t)b * S * KDIM + k;
  float acc = 0.f;
#pragma unroll 4
  for (int s2 = 0; s2 < S; ++s2) acc = fmaf(sa[s2], eb[(size_t)s2 * KDIM], acc);
  ctx[(size_t)b * KDIM + k] = acc;
  float r0 = rew[b], r1 = rew[64 + b];
  float g = (r1 > r0) ? 0.f : 1.f;
  float cv = g * tanhf(corrR[(size_t)b * 1024 + k]);
  uv[(size_t)b * 2048 + k] = cv;
  out_corrs[((size_t)b * T + t) * D + k] = cv;
  if (kt == 0 && tid < 128) out_attns[((size_t)b * T + t) * S + tid] = sa[tid];
}

// attv ctx-half GEMM + attH + bias + tanh -> uv att-half. Grid 128 x 256.
// (R10-proven verbatim.)
__global__ __launch_bounds__(256) void final_attv(
    const float* __restrict__ attH, const float* __restrict__ avW,
    const float* __restrict__ avB, const float* __restrict__ ctx,
    float* __restrict__ uv) {
  const int n0 = blockIdx.x * 8;
  const int tid = threadIdx.x;
  const int wv = __builtin_amdgcn_readfirstlane(tid >> 6);
  const int lane = tid & 63;
  __shared__ float red[4][8][64];
  float acc[8];
#pragma unroll
  for (int jj = 0; jj < 8; ++jj) acc[jj] = 0.f;
  const int k0 = wv * 256;
  const float* arow = ctx + (size_t)lane * KDIM + k0;
  for (int sc = 0; sc < 8; ++sc) {
    float av[32];
    const float4* ap = (const float4*)(arow + sc * 32);
#pragma unroll
    for (int q = 0; q < 8; ++q) {
      float4 v = ap[q];
      av[4*q] = v.x; av[4*q+1] = v.y; av[4*q+2] = v.z; av[4*q+3] = v.w;
    }
#pragma unroll
    for (int jj = 0; jj < 8; ++jj) {
      const float4* wp = (const float4*)(avW + (size_t)(n0 + jj) * 2048 + 1024 + k0 + sc * 32);
      float s = acc[jj];
#pragma unroll
      for (int q = 0; q < 8; ++q) {
        float4 w = wp[q];
        s = fmaf(av[4*q],   w.x, s);
        s = fmaf(av[4*q+1], w.y, s);
        s = fmaf(av[4*q+2], w.z, s);
        s = fmaf(av[4*q+3], w.w, s);
      }
      acc[jj] = s;
    }
  }
#pragma unroll
  for (int jj = 0; jj < 8; ++jj) red[wv][jj][lane] = acc[jj];
  __syncthreads();
  for (int idx = tid; idx < 512; idx += 256) {
    int jj = idx >> 6, bb = idx & 63;
    int n = n0 + jj;
    float v = red[0][jj][bb] + red[1][jj][bb] + red[2][jj][bb] + red[3][jj][bb]
            + attH[(size_t)n * 64 + bb] + avB[n];
    uv[(size_t)bb * 2048 + 1024 + n] = tanhf(v);
  }
}

extern "C" void kernel_launch(void* const* d_in, const int* in_sizes, int n_in,
                              void* d_out, int out_size, void* d_ws, size_t ws_size,
                              hipStream_t stream) {
  const float* reversed_input = (const float*)d_in[0];
  const float* y_states = (const float*)d_in[3];
  const float* encoder = (const float*)d_in[4];
  const float* rnn_Wih = (const float*)d_in[6];
  const float* rnn_Whh = (const float*)d_in[7];
  const float* rnn_bih = (const float*)d_in[8];
  const float* rnn_bhh = (const float*)d_in[9];
  const float* out_Wih = (const float*)d_in[10];
  const float* out_Whh = (const float*)d_in[11];
  const float* out_bih = (const float*)d_in[12];
  const float* out_bhh = (const float*)d_in[13];
  const float* corr_W = (const float*)d_in[14];
  const float* corr_b = (const float*)d_in[15];
  const float* reward_W = (const float*)d_in[16];
  const float* reward_b = (const float*)d_in[17];
  const float* attv_W = (const float*)d_in[18];
  const float* attv_b = (const float*)d_in[19];
  const float* key_W = (const float*)d_in[20];
  const float* query_W = (const float*)d_in[21];
  const float* energy_W = (const float*)d_in[22];

  float* out_corrs = (float*)d_out;                    // (B,T,D)
  float* out_rewards = out_corrs + (size_t)B * T * D;  // (B,T,2)
  float* out_attns = out_rewards + (size_t)B * T * 2;  // (B,T,S)

  // workspace (floats)
  float* p = (float*)d_ws;
  float* rnn_flip = p;  p += (size_t)B * T * H;        // [b][t][j]
  float* proj_keys = p; p += (size_t)B * S * H;
  float* part = p;      p += (size_t)6 * 64 * G3;      // [seg][b][j]
  float* h = p;         p += (size_t)B * H;
  float* uv = p;        p += (size_t)B * 2048;
  float* ctx = p;       p += (size_t)B * KDIM;
  float* corrR = p;     p += (size_t)B * 1024;
  float* pq = p;        p += (size_t)B * H;
  float* attH = p;      p += (size_t)H * 64;
  float* rew = p;       p += 128;
  float* energ = p;     p += (size_t)B * S;
  size_t fixedF = (size_t)(p - (float*)d_ws);
  int CH = 8, chLog = 3;
  {
    int c = 64, l = 6;
    for (; c >= 8; c >>= 1, --l)
      if (ws_size >= (fixedF + (size_t)c * 64 * G3) * 4) break;
    if (c < 8) { c = 8; l = 3; }
    CH = c; chLog = l;
  }
  float* gibuf = p;  // [b*CH+tl][G3] row-major

  hipMemsetAsync(h, 0, (size_t)B * H * sizeof(float), stream);
  hipMemsetAsync(uv, 0, (size_t)B * 2048 * sizeof(float), stream);

  dim3 blk(256);

  // proj_keys = encoder @ key_W^T
  gemm128<0><<<dim3(H / 128, (B * S) / 128), blk, 0, stream>>>(
      encoder, nullptr, KDIM, key_W, KDIM, nullptr, proj_keys, H, KDIM, 0, 0);

  // ---- scan 1: backward GRU (2 launches/step, JT=16) ----
  for (int c0 = 0; c0 < T; c0 += CH) {
    gemm128<1><<<dim3(G3 / 128, (64 * CH) / 128), blk, 0, stream>>>(
        reversed_input, nullptr, 0, rnn_Wih, E, rnn_bih, gibuf, G3, E, c0, chLog);
    for (int tl = 0; tl < CH; ++tl) {
      int t = c0 + tl;
      SBArgs s1{};
      s1.s[0] = { h, rnn_Whh, H, H, G3 };
      s1.s[1] = { h + 512, rnn_Whh + 512, H, H, G3 };
      sb_gemm<16><<<2 * 192, blk, 0, stream>>>(s1, 192, G3, part);
      gru_reduce<<<256, blk, 0, stream>>>(part, gibuf, CH, tl, 0, 0, 2,
                                          rnn_bhh, h, rnn_flip, t);
    }
  }

  // ---- scan 2: output GRU + attention (6 launches/step) ----
  hipMemsetAsync(h, 0, (size_t)B * H * sizeof(float), stream);
  for (int c0 = 0; c0 < T; c0 += CH) {
    gemm128<2><<<dim3(G3 / 128, (64 * CH) / 128), blk, 0, stream>>>(
        y_states, rnn_flip, 0, out_Wih, 4096, out_bih, gibuf, G3, 2048, c0, chLog);
    for (int tl = 0; tl < CH; ++tl) {
      int t = c0 + tl;
      // 1) gates GEMM (JT=32, 576 blocks): gi(uv, segs 0-3) + gh(h, segs 4-5)
      SBArgs k1{};
      for (int s2 = 0; s2 < 4; ++s2)
        k1.s[s2] = { uv + s2 * 512, out_Wih + 2048 + s2 * 512, 2048, 4096, G3 };
      for (int s2 = 0; s2 < 2; ++s2)
        k1.s[4 + s2] = { h + s2 * 512, out_Whh + s2 * 512, H, H, G3 };
      sb_gemm<32><<<6 * 96, blk, 0, stream>>>(k1, 96, G3, part);
      // 2) GRU cell
      gru_reduce<<<256, blk, 0, stream>>>(part, gibuf, CH, tl, 4, 4, 2,
                                          out_bhh, h, nullptr, t);
      // 3) h-projections (full K in-block, final values)
      hproj_gemm<<<385, blk, 0, stream>>>(h, corr_W, corr_b, query_W, attv_W,
                                          reward_W, reward_b, corrR, pq, attH,
                                          rew, out_rewards, t);
      // 4) energies
      energy_kernel<<<2048, blk, 0, stream>>>(pq, proj_keys, energy_W, energ);
      // 5) softmax + context + corr finalize + outputs
      smct_plus<<<dim3(B, 4), blk, 0, stream>>>(energ, encoder, corrR, rew,
                                                ctx, uv, out_attns, out_corrs, t);
      // 6) attv ctx-half + combine -> uv att-half
      final_attv<<<128, blk, 0, stream>>>(attH, attv_W, attv_b, ctx, uv);
    }
  }
}

// Round 17
// 22766.209 us; speedup vs baseline: 1.1705x; 1.1705x over previous
//
#include <hip/hip_runtime.h>
#include <hip/hip_bf16.h>
#include <math.h>

#define B 64
#define T 128
#define S 128
#define E 512
#define H 1024
#define D 1024
#define KDIM 1024
#define G3 3072
#define JT 16

__device__ __forceinline__ float sigmoidf_(float x) { return 1.f / (1.f + expf(-x)); }

// ---------------------------------------------------------------------------
// 128x128-tile f32 GEMM (proven R5/R8/R10/R15). SRC 0: plain A. SRC 1: rows
// (b,tl) -> reversed_input (K=512). SRC 2: rows (b,tl) -> [y_states|rnn_flip].
// ---------------------------------------------------------------------------
template<int SRC>
__global__ __launch_bounds__(256) void gemm128(
    const float* __restrict__ A1, const float* __restrict__ A2, int lda,
    const float* __restrict__ W, int ldw, const float* __restrict__ bias,
    float* __restrict__ C, int ldc, int Kd, int c0, int chLog) {
  __shared__ __align__(16) float As[16][132];
  __shared__ __align__(16) float Ws[16][132];
  const int bm = blockIdx.y * 128;
  const int bn = blockIdx.x * 128;
  const int tid = threadIdx.x;
  const int tr = tid >> 4, tc = tid & 15;
  float acc[8][8];
#pragma unroll
  for (int i = 0; i < 8; ++i)
#pragma unroll
    for (int j = 0; j < 8; ++j) acc[i][j] = 0.f;

  for (int k0 = 0; k0 < Kd; k0 += 16) {
#pragma unroll
    for (int l = 0; l < 8; ++l) {
      int i = tid + l * 256;
      int r = i >> 4, kk = i & 15;
      int rg = bm + r;
      int k = k0 + kk;
      float v;
      if (SRC == 0) {
        v = A1[(size_t)rg * lda + k];
      } else {
        int b = rg >> chLog, tl = rg & ((1 << chLog) - 1);
        int trow = b * T + c0 + tl;
        if (SRC == 1) v = A1[(size_t)trow * E + k];
        else v = (k < 1024) ? A1[(size_t)trow * 1024 + k]
                            : A2[(size_t)trow * 1024 + (k - 1024)];
      }
      As[kk][r] = v;
    }
#pragma unroll
    for (int l = 0; l < 8; ++l) {
      int i = tid + l * 256;
      int c = i >> 4, kk = i & 15;
      Ws[kk][c] = W[(size_t)(bn + c) * ldw + k0 + kk];
    }
    __syncthreads();
#pragma unroll
    for (int kk = 0; kk < 16; ++kk) {
      float a[8], w[8];
      *(float4*)&a[0] = *(const float4*)&As[kk][tr * 8];
      *(float4*)&a[4] = *(const float4*)&As[kk][tr * 8 + 4];
      *(float4*)&w[0] = *(const float4*)&Ws[kk][tc * 8];
      *(float4*)&w[4] = *(const float4*)&Ws[kk][tc * 8 + 4];
#pragma unroll
      for (int i = 0; i < 8; ++i)
#pragma unroll
        for (int j = 0; j < 8; ++j)
          acc[i][j] = fmaf(a[i], w[j], acc[i][j]);
    }
    __syncthreads();
  }
#pragma unroll
  for (int i = 0; i < 8; ++i) {
    int rg = bm + tr * 8 + i;
#pragma unroll
    for (int j = 0; j < 8; ++j) {
      int cc = bn + tc * 8 + j;
      float bv = bias ? bias[cc] : 0.f;
      C[(size_t)rg * ldc + cc] = acc[i][j] + bv;
    }
  }
}

// ---------------------------------------------------------------------------
// Scalar-broadcast skinny GEMM (R15-proven: JT=16, two-pass 64-float A cache
// for low VGPR / high occupancy). Partials [seg][b][j].
// ---------------------------------------------------------------------------
struct SBSeg { const float* A; const float* W; int lda; int ldw; int N; };
struct SBArgs { SBSeg s[6]; };

__global__ __launch_bounds__(256) void sb_gemm(SBArgs args, int jtPerSeg, int Nstr,
                                               float* __restrict__ part) {
  const int seg = blockIdx.x / jtPerSeg;
  const int jt = blockIdx.x % jtPerSeg;
  const SBSeg sg = args.s[seg];
  const int j0 = jt * JT;
  if (j0 >= sg.N) return;
  const int wv = __builtin_amdgcn_readfirstlane(threadIdx.x >> 6);
  const int lane = threadIdx.x & 63;
  float acc[JT];
#pragma unroll
  for (int jj = 0; jj < JT; ++jj) acc[jj] = 0.f;
#pragma unroll 1
  for (int half = 0; half < 2; ++half) {
    const int kw = wv * 128 + half * 64;
    float a[64];
    const float4* ap = (const float4*)(sg.A + (size_t)lane * sg.lda + kw);
#pragma unroll
    for (int q = 0; q < 16; ++q) {
      float4 v = ap[q];
      a[q * 4 + 0] = v.x; a[q * 4 + 1] = v.y; a[q * 4 + 2] = v.z; a[q * 4 + 3] = v.w;
    }
#pragma unroll
    for (int jj = 0; jj < JT; ++jj) {
      int j = j0 + jj;
      if (j < sg.N) {
        const float4* wp = (const float4*)(sg.W + (size_t)j * sg.ldw + kw);
        float s0 = 0.f, s1 = 0.f, s2 = 0.f, s3 = 0.f;
#pragma unroll
        for (int q = 0; q < 16; ++q) {
          float4 w4 = wp[q];
          s0 = fmaf(a[q * 4 + 0], w4.x, s0);
          s1 = fmaf(a[q * 4 + 1], w4.y, s1);
          s2 = fmaf(a[q * 4 + 2], w4.z, s2);
          s3 = fmaf(a[q * 4 + 3], w4.w, s3);
        }
        acc[jj] += (s0 + s1) + (s2 + s3);
      }
    }
  }
  __shared__ float red[4][JT][64];
#pragma unroll
  for (int jj = 0; jj < JT; ++jj) red[wv][jj][lane] = acc[jj];
  __syncthreads();
  for (int idx = threadIdx.x; idx < JT * 64; idx += 256) {
    int b = idx >> 4, jj = idx & 15;
    int j = j0 + jj;
    if (j < sg.N) {
      float v = red[0][jj][b] + red[1][jj][b] + red[2][jj][b] + red[3][jj][b];
      part[((size_t)seg * 64 + b) * Nstr + j] = v;
    }
  }
}

// ---------------------------------------------------------------------------
// GRU cell, fully coalesced (R10-proven verbatim). Grid 256 x 256 thr.
// ---------------------------------------------------------------------------
__global__ __launch_bounds__(256) void gru_reduce(
    const float* __restrict__ part, const float* __restrict__ gi,
    int CH, int tl, int nsGi, int ghStart, int nsGh,
    const float* __restrict__ bhh, float* __restrict__ hrow,
    float* __restrict__ flip_out, int t) {
  const int b = blockIdx.x >> 2;
  const int j = (blockIdx.x & 3) * 256 + threadIdx.x;
  const float* gb = gi + (size_t)(b * CH + tl) * G3;
  float gir = gb[j];
  float giz = gb[H + j];
  float gin = gb[2 * H + j];
  for (int p2 = 0; p2 < nsGi; ++p2) {
    const float* pp = part + ((size_t)p2 * 64 + b) * G3;
    gir += pp[j]; giz += pp[H + j]; gin += pp[2 * H + j];
  }
  float ghr = bhh[j], ghz = bhh[H + j], ghn = bhh[2 * H + j];
  for (int p2 = ghStart; p2 < ghStart + nsGh; ++p2) {
    const float* pp = part + ((size_t)p2 * 64 + b) * G3;
    ghr += pp[j]; ghz += pp[H + j]; ghn += pp[2 * H + j];
  }
  float r = sigmoidf_(gir + ghr);
  float z = sigmoidf_(giz + ghz);
  float n = tanhf(gin + r * ghn);
  float hold = hrow[(size_t)b * H + j];
  float hnew = (1.f - z) * n + z * hold;
  hrow[(size_t)b * H + j] = hnew;
  if (flip_out)
    flip_out[(size_t)b * T * H + (size_t)(T - 1 - t) * H + j] = hnew;
}

// ---------------------------------------------------------------------------
// h-projections, full K=1024 in-block. Grid 385 (R10-proven verbatim).
// ---------------------------------------------------------------------------
__global__ __launch_bounds__(256) void hproj_gemm(
    const float* __restrict__ h,
    const float* __restrict__ corrW, const float* __restrict__ corrB,
    const float* __restrict__ qW, const float* __restrict__ avW,
    const float* __restrict__ rewW, const float* __restrict__ rewB,
    float* __restrict__ corrR, float* __restrict__ pq,
    float* __restrict__ attH, float* __restrict__ rew,
    float* __restrict__ out_rewards, int t) {
  const int task = blockIdx.x;
  const int tid = threadIdx.x;
  const int wv = __builtin_amdgcn_readfirstlane(tid >> 6);
  const int lane = tid & 63;
  const float* Wb; int ldw = 1024, n0, nrows, typ;
  if (task < 128)      { Wb = corrW; n0 = task * 8;         nrows = 8; typ = 0; }
  else if (task < 256) { Wb = qW;    n0 = (task - 128) * 8; nrows = 8; typ = 1; }
  else if (task < 384) { Wb = avW;   n0 = (task - 256) * 8; nrows = 8; typ = 2; ldw = 2048; }
  else                 { Wb = rewW;  n0 = 0;                nrows = 2; typ = 3; }
  const int k0 = wv * 256;
  const float* arow = h + (size_t)lane * H + k0;
  float acc[8] = {0.f, 0.f, 0.f, 0.f, 0.f, 0.f, 0.f, 0.f};
  for (int sc = 0; sc < 8; ++sc) {
    float av[32];
    const float4* ap = (const float4*)(arow + sc * 32);
#pragma unroll
    for (int q = 0; q < 8; ++q) {
      float4 v = ap[q];
      av[4*q] = v.x; av[4*q+1] = v.y; av[4*q+2] = v.z; av[4*q+3] = v.w;
    }
#pragma unroll
    for (int rr = 0; rr < 8; ++rr) {
      if (rr < nrows) {
        const float4* wp = (const float4*)(Wb + (size_t)(n0 + rr) * ldw + k0 + sc * 32);
        float s = acc[rr];
#pragma unroll
        for (int q = 0; q < 8; ++q) {
          float4 w = wp[q];
          s = fmaf(av[4*q],   w.x, s);
          s = fmaf(av[4*q+1], w.y, s);
          s = fmaf(av[4*q+2], w.z, s);
          s = fmaf(av[4*q+3], w.w, s);
        }
        acc[rr] = s;
      }
    }
  }
  __shared__ float red[4][8][64];
#pragma unroll
  for (int rr = 0; rr < 8; ++rr) red[wv][rr][lane] = acc[rr];
  __syncthreads();
  for (int idx = tid; idx < 512; idx += 256) {
    int b = idx >> 3, jj = idx & 7;
    if (jj < nrows) {
      int n = n0 + jj;
      float v = red[0][jj][b] + red[1][jj][b] + red[2][jj][b] + red[3][jj][b];
      if (typ == 0) corrR[(size_t)b * 1024 + n] = v + corrB[n];
      else if (typ == 1) pq[(size_t)b * 1024 + n] = v;
      else if (typ == 2) attH[(size_t)n * 64 + b] = v;
      else {
        float rv = v + rewB[n];
        rew[n * 64 + b] = rv;
        out_rewards[((size_t)b * T + t) * 2 + n] = rv;
      }
    }
  }
}

// energies: wave per (b,s). Grid 2048 x 256. (R3/R10-proven verbatim.)
__global__ __launch_bounds__(256) void energy_kernel(
    const float* __restrict__ pq, const float* __restrict__ pk,
    const float* __restrict__ eW, float* __restrict__ energies) {
  int wid = blockIdx.x * 4 + (threadIdx.x >> 6);
  int lane = threadIdx.x & 63;
  int b = wid >> 7, s = wid & 127;
  const float* pkp = pk + ((size_t)b * S + s) * H;
  const float* qp = pq + (size_t)b * H;
  float acc = 0.f;
#pragma unroll
  for (int i = 0; i < 16; ++i) {
    int j = lane + i * 64;
    acc += tanhf(qp[j] + pkp[j]) * eW[j];
  }
#pragma unroll
  for (int off = 32; off > 0; off >>= 1) acc += __shfl_down(acc, off);
  if (lane == 0) energies[b * S + s] = acc;
}

// Softmax (redundant per kt) + context + corr finalize + outputs.
// Grid (64, 4) x 256. (R10-proven verbatim.)
__global__ __launch_bounds__(256) void smct_plus(
    const float* __restrict__ energies, const float* __restrict__ enc,
    const float* __restrict__ corrR, const float* __restrict__ rew,
    float* __restrict__ ctx, float* __restrict__ uv,
    float* __restrict__ out_attns, float* __restrict__ out_corrs, int t) {
  int b = blockIdx.x, kt = blockIdx.y;
  int tid = threadIdx.x;
  __shared__ float se[128], sa[128], ss[128];
  if (tid < 128) { se[tid] = energies[b * S + tid]; sa[tid] = se[tid]; }
  __syncthreads();
  for (int st2 = 64; st2 > 0; st2 >>= 1) {
    if (tid < st2) sa[tid] = fmaxf(sa[tid], sa[tid + st2]);
    __syncthreads();
  }
  float mx = sa[0];
  __syncthreads();
  if (tid < 128) { sa[tid] = expf(se[tid] - mx); ss[tid] = sa[tid]; }
  __syncthreads();
  for (int st2 = 64; st2 > 0; st2 >>= 1) {
    if (tid < st2) ss[tid] += ss[tid + st2];
    __syncthreads();
  }
  float inv = 1.f / ss[0];
  __syncthreads();
  if (tid < 128) sa[tid] *= inv;
  __syncthreads();
  int k = kt * 256 + tid;
  const float* eb = enc + (size_t)b * S * KDIM + k;
  float acc = 0.f;
#pragma unroll 4
  for (int s2 = 0; s2 < S; ++s2) acc = fmaf(sa[s2], eb[(size_t)s2 * KDIM], acc);
  ctx[(size_t)b * KDIM + k] = acc;
  float r0 = rew[b], r1 = rew[64 + b];
  float g = (r1 > r0) ? 0.f : 1.f;
  float cv = g * tanhf(corrR[(size_t)b * 1024 + k]);
  uv[(size_t)b * 2048 + k] = cv;
  out_corrs[((size_t)b * T + t) * D + k] = cv;
  if (kt == 0 && tid < 128) out_attns[((size_t)b * T + t) * S + tid] = sa[tid];
}

// attv ctx-half GEMM + attH + bias + tanh -> uv att-half. Grid 128 x 256.
// (R10-proven verbatim.)
__global__ __launch_bounds__(256) void final_attv(
    const float* __restrict__ attH, const float* __restrict__ avW,
    const float* __restrict__ avB, const float* __restrict__ ctx,
    float* __restrict__ uv) {
  const int n0 = blockIdx.x * 8;
  const int tid = threadIdx.x;
  const int wv = __builtin_amdgcn_readfirstlane(tid >> 6);
  const int lane = tid & 63;
  __shared__ float red[4][8][64];
  float acc[8];
#pragma unroll
  for (int jj = 0; jj < 8; ++jj) acc[jj] = 0.f;
  const int k0 = wv * 256;
  const float* arow = ctx + (size_t)lane * KDIM + k0;
  for (int sc = 0; sc < 8; ++sc) {
    float av[32];
    const float4* ap = (const float4*)(arow + sc * 32);
#pragma unroll
    for (int q = 0; q < 8; ++q) {
      float4 v = ap[q];
      av[4*q] = v.x; av[4*q+1] = v.y; av[4*q+2] = v.z; av[4*q+3] = v.w;
    }
#pragma unroll
    for (int jj = 0; jj < 8; ++jj) {
      const float4* wp = (const float4*)(avW + (size_t)(n0 + jj) * 2048 + 1024 + k0 + sc * 32);
      float s = acc[jj];
#pragma unroll
      for (int q = 0; q < 8; ++q) {
        float4 w = wp[q];
        s = fmaf(av[4*q],   w.x, s);
        s = fmaf(av[4*q+1], w.y, s);
        s = fmaf(av[4*q+2], w.z, s);
        s = fmaf(av[4*q+3], w.w, s);
      }
      acc[jj] = s;
    }
  }
#pragma unroll
  for (int jj = 0; jj < 8; ++jj) red[wv][jj][lane] = acc[jj];
  __syncthreads();
  for (int idx = tid; idx < 512; idx += 256) {
    int jj = idx >> 6, bb = idx & 63;
    int n = n0 + jj;
    float v = red[0][jj][bb] + red[1][jj][bb] + red[2][jj][bb] + red[3][jj][bb]
            + attH[(size_t)n * 64 + bb] + avB[n];
    uv[(size_t)bb * 2048 + 1024 + n] = tanhf(v);
  }
}

extern "C" void kernel_launch(void* const* d_in, const int* in_sizes, int n_in,
                              void* d_out, int out_size, void* d_ws, size_t ws_size,
                              hipStream_t stream) {
  const float* reversed_input = (const float*)d_in[0];
  const float* y_states = (const float*)d_in[3];
  const float* encoder = (const float*)d_in[4];
  const float* rnn_Wih = (const float*)d_in[6];
  const float* rnn_Whh = (const float*)d_in[7];
  const float* rnn_bih = (const float*)d_in[8];
  const float* rnn_bhh = (const float*)d_in[9];
  const float* out_Wih = (const float*)d_in[10];
  const float* out_Whh = (const float*)d_in[11];
  const float* out_bih = (const float*)d_in[12];
  const float* out_bhh = (const float*)d_in[13];
  const float* corr_W = (const float*)d_in[14];
  const float* corr_b = (const float*)d_in[15];
  const float* reward_W = (const float*)d_in[16];
  const float* reward_b = (const float*)d_in[17];
  const float* attv_W = (const float*)d_in[18];
  const float* attv_b = (const float*)d_in[19];
  const float* key_W = (const float*)d_in[20];
  const float* query_W = (const float*)d_in[21];
  const float* energy_W = (const float*)d_in[22];

  float* out_corrs = (float*)d_out;                    // (B,T,D)
  float* out_rewards = out_corrs + (size_t)B * T * D;  // (B,T,2)
  float* out_attns = out_rewards + (size_t)B * T * 2;  // (B,T,S)

  // workspace (floats)
  float* p = (float*)d_ws;
  float* rnn_flip = p;  p += (size_t)B * T * H;        // [b][t][j]
  float* proj_keys = p; p += (size_t)B * S * H;
  float* part = p;      p += (size_t)6 * 64 * G3;      // [seg][b][j]
  float* h = p;         p += (size_t)B * H;
  float* uv = p;        p += (size_t)B * 2048;
  float* ctx = p;       p += (size_t)B * KDIM;
  float* corrR = p;     p += (size_t)B * 1024;
  float* pq = p;        p += (size_t)B * H;
  float* attH = p;      p += (size_t)H * 64;
  float* rew = p;       p += 128;
  float* energ = p;     p += (size_t)B * S;
  size_t fixedF = (size_t)(p - (float*)d_ws);
  // CH capped at 32: gibuf 25 MB keeps the scan-2 stream set (~190 MB)
  // well inside the 256 MB L3 (R5 lesson, conservative application).
  int CH = 8, chLog = 3;
  {
    int c = 32, l = 5;
    for (; c >= 8; c >>= 1, --l)
      if (ws_size >= (fixedF + (size_t)c * 64 * G3) * 4) break;
    if (c < 8) { c = 8; l = 3; }
    CH = c; chLog = l;
  }
  float* gibuf = p;  // [b*CH+tl][G3] row-major

  hipMemsetAsync(h, 0, (size_t)B * H * sizeof(float), stream);
  hipMemsetAsync(uv, 0, (size_t)B * 2048 * sizeof(float), stream);

  dim3 blk(256);

  // proj_keys = encoder @ key_W^T
  gemm128<0><<<dim3(H / 128, (B * S) / 128), blk, 0, stream>>>(
      encoder, nullptr, KDIM, key_W, KDIM, nullptr, proj_keys, H, KDIM, 0, 0);

  // ---- scan 1: backward GRU (2 launches/step) ----
  for (int c0 = 0; c0 < T; c0 += CH) {
    gemm128<1><<<dim3(G3 / 128, (64 * CH) / 128), blk, 0, stream>>>(
        reversed_input, nullptr, 0, rnn_Wih, E, rnn_bih, gibuf, G3, E, c0, chLog);
    for (int tl = 0; tl < CH; ++tl) {
      int t = c0 + tl;
      SBArgs s1{};
      s1.s[0] = { h, rnn_Whh, H, H, G3 };
      s1.s[1] = { h + 512, rnn_Whh + 512, H, H, G3 };
      sb_gemm<<<2 * 192, blk, 0, stream>>>(s1, 192, G3, part);
      gru_reduce<<<256, blk, 0, stream>>>(part, gibuf, CH, tl, 0, 0, 2,
                                          rnn_bhh, h, rnn_flip, t);
    }
  }

  // ---- scan 2: output GRU + attention (6 launches/step) ----
  hipMemsetAsync(h, 0, (size_t)B * H * sizeof(float), stream);
  for (int c0 = 0; c0 < T; c0 += CH) {
    gemm128<2><<<dim3(G3 / 128, (64 * CH) / 128), blk, 0, stream>>>(
        y_states, rnn_flip, 0, out_Wih, 4096, out_bih, gibuf, G3, 2048, c0, chLog);
    for (int tl = 0; tl < CH; ++tl) {
      int t = c0 + tl;
      // 1) gates GEMM: gi(uv, K=2048, segs 0-3) + gh(h, K=1024, segs 4-5)
      SBArgs k1{};
      for (int s2 = 0; s2 < 4; ++s2)
        k1.s[s2] = { uv + s2 * 512, out_Wih + 2048 + s2 * 512, 2048, 4096, G3 };
      for (int s2 = 0; s2 < 2; ++s2)
        k1.s[4 + s2] = { h + s2 * 512, out_Whh + s2 * 512, H, H, G3 };
      sb_gemm<<<6 * 192, blk, 0, stream>>>(k1, 192, G3, part);
      // 2) GRU cell
      gru_reduce<<<256, blk, 0, stream>>>(part, gibuf, CH, tl, 4, 4, 2,
                                          out_bhh, h, nullptr, t);
      // 3) h-projections (full K in-block, final values)
      hproj_gemm<<<385, blk, 0, stream>>>(h, corr_W, corr_b, query_W, attv_W,
                                          reward_W, reward_b, corrR, pq, attH,
                                          rew, out_rewards, t);
      // 4) energies
      energy_kernel<<<2048, blk, 0, stream>>>(pq, proj_keys, energy_W, energ);
      // 5) softmax + context + corr finalize + outputs
      smct_plus<<<dim3(B, 4), blk, 0, stream>>>(energ, encoder, corrR, rew,
                                                ctx, uv, out_attns, out_corrs, t);
      // 6) attv ctx-half + combine -> uv att-half
      final_attv<<<128, blk, 0, stream>>>(attH, attv_W, attv_b, ctx, uv);
    }
  }
}